// Round 6
// baseline (1330.692 us; speedup 1.0000x reference)
//
#include <hip/hip_runtime.h>
#include <hip/hip_bf16.h>
#include <cstdint>

typedef __bf16 bf16;
typedef __bf16 bf16x8 __attribute__((ext_vector_type(8)));
typedef __bf16 bf16x4 __attribute__((ext_vector_type(4)));
typedef float f32x4 __attribute__((ext_vector_type(4)));

#define DEV __device__ __forceinline__

DEV float wred_sum(float v) {
#pragma unroll
  for (int off = 32; off > 0; off >>= 1) v += __shfl_xor(v, off, 64);
  return v;
}
DEV float wred_max(float v) {
#pragma unroll
  for (int off = 32; off > 0; off >>= 1) v = fmaxf(v, __shfl_xor(v, off, 64));
  return v;
}

// ---------------- weight convert + transpose: in [K,N] f32 -> out [N,K] bf16
__global__ void convT_kernel(const float* __restrict__ in, bf16* __restrict__ out,
                             int K, int N) {
  __shared__ float t[32][33];
  const int n0 = blockIdx.x * 32, k0 = blockIdx.y * 32;
  const int tx = threadIdx.x & 31, ty = threadIdx.x >> 5;  // 32x8
#pragma unroll
  for (int i = 0; i < 4; i++)
    t[ty + 8 * i][tx] = in[(long)(k0 + ty + 8 * i) * N + n0 + tx];
  __syncthreads();
#pragma unroll
  for (int i = 0; i < 4; i++)
    out[(long)(n0 + ty + 8 * i) * K + k0 + tx] = (bf16)t[tx][ty + 8 * i];
}

// ---------------- bf16 transpose: in [R,C] (ldin) -> out [C,R] (ldout)
__global__ void transpose_bf16(const bf16* __restrict__ in, bf16* __restrict__ out,
                               int ldin, int ldout) {
  __shared__ bf16 t[32][33];
  const int c0 = blockIdx.x * 32, r0 = blockIdx.y * 32;
  const int tx = threadIdx.x & 31, ty = threadIdx.x >> 5;  // 32x8
#pragma unroll
  for (int i = 0; i < 4; i++)
    t[ty + 8 * i][tx] = in[(long)(r0 + ty + 8 * i) * ldin + c0 + tx];
  __syncthreads();
#pragma unroll
  for (int i = 0; i < 4; i++)
    out[(long)(c0 + ty + 8 * i) * ldout + r0 + tx] = t[tx][ty + 8 * i];
}

// ---------------- layernorm (row=1024) f32 -> bf16
__global__ void ln_bf16_kernel(const float* __restrict__ x, const float* __restrict__ g,
                               const float* __restrict__ be, bf16* __restrict__ out) {
  const long row = blockIdx.x;
  const int tid = threadIdx.x;  // 256
  const float4 v = ((const float4*)(x + row * 1024))[tid];
  float s = v.x + v.y + v.z + v.w;
  float s2 = v.x * v.x + v.y * v.y + v.z * v.z + v.w * v.w;
  __shared__ float rs_[4], rs2_[4];
  s = wred_sum(s);
  s2 = wred_sum(s2);
  const int wave = tid >> 6, lane = tid & 63;
  if (lane == 0) { rs_[wave] = s; rs2_[wave] = s2; }
  __syncthreads();
  s = rs_[0] + rs_[1] + rs_[2] + rs_[3];
  s2 = rs2_[0] + rs2_[1] + rs2_[2] + rs2_[3];
  const float mu = s * (1.0f / 1024.0f);
  const float var = s2 * (1.0f / 1024.0f) - mu * mu;
  const float rstd = rsqrtf(var + 1e-5f);
  const float4 gg = ((const float4*)g)[tid];
  const float4 bb = ((const float4*)be)[tid];
  bf16x4 o;
  o[0] = (bf16)((v.x - mu) * rstd * gg.x + bb.x);
  o[1] = (bf16)((v.y - mu) * rstd * gg.y + bb.y);
  o[2] = (bf16)((v.z - mu) * rstd * gg.z + bb.z);
  o[3] = (bf16)((v.w - mu) * rstd * gg.w + bb.w);
  *(bf16x4*)(out + row * 1024 + tid * 4) = o;
}

// ---------------- softmax over rows of 4096, in-place bf16
__global__ void softmax_kernel(bf16* __restrict__ p) {
  const long row = blockIdx.x;
  bf16* pr = p + row * 4096;
  const int tid = threadIdx.x;  // 256, 16 elems each
  bf16x8 a = *(const bf16x8*)(pr + tid * 16);
  bf16x8 b = *(const bf16x8*)(pr + tid * 16 + 8);
  float v[16];
#pragma unroll
  for (int i = 0; i < 8; i++) { v[i] = (float)a[i]; v[8 + i] = (float)b[i]; }
  float mx = -1e30f;
#pragma unroll
  for (int i = 0; i < 16; i++) mx = fmaxf(mx, v[i]);
  __shared__ float red1[4], red2[4];
  mx = wred_max(mx);
  const int wave = tid >> 6, lane = tid & 63;
  if (lane == 0) red1[wave] = mx;
  __syncthreads();
  mx = fmaxf(fmaxf(red1[0], red1[1]), fmaxf(red1[2], red1[3]));
  float s = 0.0f;
#pragma unroll
  for (int i = 0; i < 16; i++) { v[i] = __expf(v[i] - mx); s += v[i]; }
  s = wred_sum(s);
  if (lane == 0) red2[wave] = s;
  __syncthreads();
  s = red2[0] + red2[1] + red2[2] + red2[3];
  const float inv = 1.0f / s;
#pragma unroll
  for (int i = 0; i < 8; i++) { a[i] = (bf16)(v[i] * inv); b[i] = (bf16)(v[8 + i] * inv); }
  *(bf16x8*)(pr + tid * 16) = a;
  *(bf16x8*)(pr + tid * 16 + 8) = b;
}

enum { EPI_BF16 = 0, EPI_QKV = 1, EPI_GELU = 2, EPI_F32RES = 3 };

DEV void stage16(const bf16* g, bf16* l) {
  __builtin_amdgcn_global_load_lds((const __attribute__((address_space(1))) void*)g,
                                   (__attribute__((address_space(3))) void*)l, 16, 0, 0);
}

DEV int xcd_swizzle(int flat, int nwg) {
  const int qq = nwg >> 3, rr = nwg & 7;
  const int xcd = flat & 7, idx = flat >> 3;
  return (xcd < rr ? xcd * (qq + 1) : rr * (qq + 1) + (xcd - rr) * qq) + idx;
}

// ---------------- 128x128 double-buffered 2-phase NT GEMM (64 KiB static LDS)
// For the big-grid shapes (QKV/scores/W1/WO: 768-1024 blocks -> 2 RESIDENT
// blocks/CU; m114 implicit overlap hides the vmcnt(0)+barrier drain).
// 256 threads = 4 waves (2M x 2N), BK=64. Measured R3 structure (77 us at
// 1-resident); residency is the new lever.
template <int EPI>
__global__ __launch_bounds__(256, 2)
void gemm128(const bf16* __restrict__ A, const bf16* __restrict__ B,
             const float* __restrict__ bias, const float* bias2, const float* bias3,
             const float* resid, void* Cout, int M, int N, int K,
             int lda, int ldb, int ldc, float alpha) {
  __shared__ __align__(16) bf16 sA[2 * 8192];  // [buf][128 rows][64 cols]
  __shared__ __align__(16) bf16 sB[2 * 8192];
  int flat = (int)(blockIdx.y * gridDim.x + blockIdx.x);
  flat = xcd_swizzle(flat, (int)(gridDim.x * gridDim.y));
  const int bix = flat % (int)gridDim.x, biy = flat / (int)gridDim.x;
  const int tid = threadIdx.x;
  const int lane = tid & 63;
  const int wid = tid >> 6;          // 0..3
  const int q = lane >> 4, r16 = lane & 15;
  const int wr = wid >> 1, wc = wid & 1;
  const long m0 = (long)biy * 128;
  const long n0 = (long)bix * 128;
  const int srow = tid >> 3;         // 0..31 (8 threads/row, 16B each)
  const int gcol = ((tid & 7) ^ (srow & 7)) * 8;   // pre-swizzled source chunk
  const long lda32 = (long)lda * 32, ldb32 = (long)ldb * 32;
  const bf16* Ag = A + (m0 + srow) * (long)lda + gcol;
  const bf16* Bg = B + (n0 + srow) * (long)ldb + gcol;
  const int NT = K >> 6;
  const int swz = r16 * 64 + ((q ^ (r16 & 7)) * 8);
  const int abase = wr * 4096 + swz;   // row block wr*64
  const int bbase = wc * 4096 + swz;
  f32x4 acc[4][4] = {};

  // prologue: tile 0 -> buf0
#pragma unroll
  for (int blk = 0; blk < 4; ++blk) {
    stage16(Ag + blk * lda32, sA + tid * 8 + blk * 2048);
    stage16(Bg + blk * ldb32, sB + tid * 8 + blk * 2048);
  }
  asm volatile("s_waitcnt vmcnt(0)" ::: "memory");
  __builtin_amdgcn_sched_barrier(0);
  __builtin_amdgcn_s_barrier();
  __builtin_amdgcn_sched_barrier(0);

  for (int t = 0; t < NT; ++t) {
    const int bx = (t & 1) * 8192;
    const int nbx = 8192 - bx;
    if (t + 1 < NT) {   // stage next tile into the other buffer
      const bf16* Agn = Ag + (t + 1) * 64;
      const bf16* Bgn = Bg + (t + 1) * 64;
#pragma unroll
      for (int blk = 0; blk < 4; ++blk) {
        stage16(Agn + blk * lda32, sA + nbx + tid * 8 + blk * 2048);
        stage16(Bgn + blk * ldb32, sB + nbx + tid * 8 + blk * 2048);
      }
    }
    const bf16* sAb = sA + bx;
    const bf16* sBb = sB + bx;
    bf16x8 a0[4], a1[4], b0[4], b1[4];
#pragma unroll
    for (int i = 0; i < 4; ++i) {
      a0[i] = *(const bf16x8*)(sAb + (abase + i * 1024));
      a1[i] = *(const bf16x8*)(sAb + ((abase + i * 1024) ^ 32));
      b0[i] = *(const bf16x8*)(sBb + (bbase + i * 1024));
      b1[i] = *(const bf16x8*)(sBb + ((bbase + i * 1024) ^ 32));
    }
#pragma unroll
    for (int i = 0; i < 4; ++i)
#pragma unroll
      for (int j = 0; j < 4; ++j) {  // swapped operand order -> row/col C/D map
        acc[i][j] = __builtin_amdgcn_mfma_f32_16x16x32_bf16(b0[j], a0[i], acc[i][j], 0, 0, 0);
        acc[i][j] = __builtin_amdgcn_mfma_f32_16x16x32_bf16(b1[j], a1[i], acc[i][j], 0, 0, 0);
      }
    if (t + 1 < NT) {
      asm volatile("s_waitcnt vmcnt(0)" ::: "memory");
      __builtin_amdgcn_sched_barrier(0);
      __builtin_amdgcn_s_barrier();
      __builtin_amdgcn_sched_barrier(0);
    }
  }

  // epilogue (row = m-frag r16, 4 consecutive cols per lane)
#pragma unroll
  for (int i = 0; i < 4; ++i) {
    const long row = m0 + wr * 64 + i * 16 + r16;
#pragma unroll
    for (int j = 0; j < 4; ++j) {
      const int ncol = (int)n0 + wc * 64 + j * 16 + q * 4;
      float4 b4 = make_float4(0.f, 0.f, 0.f, 0.f);
      if (EPI == EPI_QKV) {
        const int band = ncol >> 10;
        const float* bsel = band == 0 ? bias : (band == 1 ? bias2 : bias3);
        b4 = *(const float4*)(bsel + (ncol & 1023));
      } else if (bias != nullptr) {
        b4 = *(const float4*)(bias + ncol);
      }
      float v0 = acc[i][j][0] * alpha + b4.x;
      float v1 = acc[i][j][1] * alpha + b4.y;
      float v2 = acc[i][j][2] * alpha + b4.z;
      float v3 = acc[i][j][3] * alpha + b4.w;
      if (EPI == EPI_GELU) {
        v0 = 0.5f * v0 * (1.0f + erff(v0 * 0.70710678118654752f));
        v1 = 0.5f * v1 * (1.0f + erff(v1 * 0.70710678118654752f));
        v2 = 0.5f * v2 * (1.0f + erff(v2 * 0.70710678118654752f));
        v3 = 0.5f * v3 * (1.0f + erff(v3 * 0.70710678118654752f));
      }
      if (EPI == EPI_F32RES) {
        const long idx = row * (long)ldc + ncol;
        const float4 rr = *(const float4*)(resid + idx);
        const float4 o = make_float4(v0 + rr.x, v1 + rr.y, v2 + rr.z, v3 + rr.w);
        *(float4*)((float*)Cout + idx) = o;
      } else {
        bf16x4 o;
        o[0] = (bf16)v0; o[1] = (bf16)v1; o[2] = (bf16)v2; o[3] = (bf16)v3;
        *(bf16x4*)((bf16*)Cout + row * (long)ldc + ncol) = o;
      }
    }
  }
}

// ---------------- 64x128 triple-buffered NT GEMM, 2-tiles-ahead (PV, W2)
// N=1024 locks the 128-col grid dim at 8; splitting M to 64 gives grid
// (8,64) = 512 blocks = 2 RESIDENT blocks/CU (LDS 72 KiB) + deep prefetch.
// 256 threads = 4 waves (2M x 2N), per-wave 32x64; BK=64; 6 loads/tile;
// counted vmcnt(6): t+1 landed, t+2 in flight.
template <int EPI>
__global__ __launch_bounds__(256, 2)
void gemm64(const bf16* __restrict__ A, const bf16* __restrict__ B,
            const float* __restrict__ bias, const float* __restrict__ resid,
            void* Cout, int M, int N, int K,
            int lda, int ldb, int ldc, float alpha) {
  extern __shared__ __align__(16) char smem[];
  bf16* sA = (bf16*)smem;        // 3 bufs x 4096 bf16 (64 rows x 64)
  bf16* sB = sA + 3 * 4096;      // 3 bufs x 8192 bf16 (128 rows x 64)
  int flat = (int)(blockIdx.y * gridDim.x + blockIdx.x);
  flat = xcd_swizzle(flat, (int)(gridDim.x * gridDim.y));
  const int bix = flat % (int)gridDim.x, biy = flat / (int)gridDim.x;
  const int tid = threadIdx.x;
  const int lane = tid & 63;
  const int wid = tid >> 6;          // 0..3
  const int q = lane >> 4, r16 = lane & 15;
  const int wr = wid >> 1, wc = wid & 1;   // wr: 32-row band, wc: 64-col band
  const long m0 = (long)biy * 64;
  const long n0 = (long)bix * 128;
  const int srow = tid >> 3;         // 0..31
  const int gcol = ((tid & 7) ^ (srow & 7)) * 8;
  const long lda32 = (long)lda * 32, ldb32 = (long)ldb * 32;
  const bf16* Ag = A + (m0 + srow) * (long)lda + gcol;
  const bf16* Bg = B + (n0 + srow) * (long)ldb + gcol;
  const int NT = K >> 6;
  const int swz = r16 * 64 + ((q ^ (r16 & 7)) * 8);
  const int abase = wr * 2048 + swz;   // 32-row band
  const int bbase = wc * 4096 + swz;   // 64-row band
  f32x4 acc[2][4] = {};

  // prologue: tiles 0,1 -> bufs 0,1 (6 loads each: 2 A-blocks + 4 B-blocks)
  const int PRE = NT < 2 ? NT : 2;
  for (int tt = 0; tt < PRE; ++tt) {
#pragma unroll
    for (int blk = 0; blk < 2; ++blk)
      stage16(Ag + tt * 64 + blk * lda32, sA + tt * 4096 + tid * 8 + blk * 2048);
#pragma unroll
    for (int blk = 0; blk < 4; ++blk)
      stage16(Bg + tt * 64 + blk * ldb32, sB + tt * 8192 + tid * 8 + blk * 2048);
  }
  if (NT >= 2) asm volatile("s_waitcnt vmcnt(6)" ::: "memory");
  else         asm volatile("s_waitcnt vmcnt(0)" ::: "memory");
  __builtin_amdgcn_sched_barrier(0);
  __builtin_amdgcn_s_barrier();
  __builtin_amdgcn_sched_barrier(0);

  int bxA = 0, bxB = 0;          // compute-buf offsets (t%3)
  int bsA = 8192, bsB = 16384;   // stage-buf offsets ((t+2)%3)
  for (int t = 0; t < NT; ++t) {
    if (t + 2 < NT) {   // stage tile t+2 (its buf's last read was tile t-1)
      const bf16* Agn = Ag + (t + 2) * 64;
      const bf16* Bgn = Bg + (t + 2) * 64;
#pragma unroll
      for (int blk = 0; blk < 2; ++blk)
        stage16(Agn + blk * lda32, sA + bsA + tid * 8 + blk * 2048);
#pragma unroll
      for (int blk = 0; blk < 4; ++blk)
        stage16(Bgn + blk * ldb32, sB + bsB + tid * 8 + blk * 2048);
    }
    const bf16* sAb = sA + bxA;
    const bf16* sBb = sB + bxB;
    bf16x8 a0[2], a1[2], b0[4], b1[4];
#pragma unroll
    for (int i = 0; i < 2; ++i) {
      a0[i] = *(const bf16x8*)(sAb + (abase + i * 1024));
      a1[i] = *(const bf16x8*)(sAb + ((abase + i * 1024) ^ 32));
    }
#pragma unroll
    for (int j = 0; j < 4; ++j) {
      b0[j] = *(const bf16x8*)(sBb + (bbase + j * 1024));
      b1[j] = *(const bf16x8*)(sBb + ((bbase + j * 1024) ^ 32));
    }
#pragma unroll
    for (int i = 0; i < 2; ++i)
#pragma unroll
      for (int j = 0; j < 4; ++j) {
        acc[i][j] = __builtin_amdgcn_mfma_f32_16x16x32_bf16(b0[j], a0[i], acc[i][j], 0, 0, 0);
        acc[i][j] = __builtin_amdgcn_mfma_f32_16x16x32_bf16(b1[j], a1[i], acc[i][j], 0, 0, 0);
      }
    if (t + 2 < NT)      asm volatile("s_waitcnt vmcnt(6)" ::: "memory");
    else if (t + 1 < NT) asm volatile("s_waitcnt vmcnt(0)" ::: "memory");
    if (t + 1 < NT) {
      __builtin_amdgcn_sched_barrier(0);
      __builtin_amdgcn_s_barrier();
      __builtin_amdgcn_sched_barrier(0);
    }
    bxA += 4096; if (bxA == 12288) bxA = 0;
    bxB += 8192; if (bxB == 24576) bxB = 0;
    bsA += 4096; if (bsA == 12288) bsA = 0;
    bsB += 8192; if (bsB == 24576) bsB = 0;
  }

  // epilogue
#pragma unroll
  for (int i = 0; i < 2; ++i) {
    const long row = m0 + wr * 32 + i * 16 + r16;
#pragma unroll
    for (int j = 0; j < 4; ++j) {
      const int ncol = (int)n0 + wc * 64 + j * 16 + q * 4;
      float4 b4 = make_float4(0.f, 0.f, 0.f, 0.f);
      if (bias != nullptr) b4 = *(const float4*)(bias + ncol);
      float v0 = acc[i][j][0] * alpha + b4.x;
      float v1 = acc[i][j][1] * alpha + b4.y;
      float v2 = acc[i][j][2] * alpha + b4.z;
      float v3 = acc[i][j][3] * alpha + b4.w;
      if (EPI == EPI_F32RES) {
        const long idx = row * (long)ldc + ncol;
        const float4 rr = *(const float4*)(resid + idx);
        const float4 o = make_float4(v0 + rr.x, v1 + rr.y, v2 + rr.z, v3 + rr.w);
        *(float4*)((float*)Cout + idx) = o;
      } else {
        bf16x4 o;
        o[0] = (bf16)v0; o[1] = (bf16)v1; o[2] = (bf16)v2; o[3] = (bf16)v3;
        *(bf16x4*)((bf16*)Cout + row * (long)ldc + ncol) = o;
      }
    }
  }
}

extern "C" void kernel_launch(void* const* d_in, const int* in_sizes, int n_in,
                              void* d_out, int out_size, void* d_ws, size_t ws_size,
                              hipStream_t stream) {
  const float* x  = (const float*)d_in[0];
  const float* wq = (const float*)d_in[1];
  const float* bq = (const float*)d_in[2];
  const float* wk = (const float*)d_in[3];
  const float* bk = (const float*)d_in[4];
  const float* wv = (const float*)d_in[5];
  const float* bv = (const float*)d_in[6];
  const float* wo = (const float*)d_in[7];
  const float* bo = (const float*)d_in[8];
  const float* w1 = (const float*)d_in[9];
  const float* b1 = (const float*)d_in[10];
  const float* w2 = (const float*)d_in[11];
  const float* b2 = (const float*)d_in[12];
  const float* g1 = (const float*)d_in[13];
  const float* be1 = (const float*)d_in[14];
  const float* g2 = (const float*)d_in[15];
  const float* be2 = (const float*)d_in[16];

  // allow >64 KiB dynamic LDS for gemm64 (once per process)
  static int attr_done = 0;
  if (!attr_done) {
    attr_done = 1;
    hipFuncSetAttribute(reinterpret_cast<const void*>(&gemm64<EPI_BF16>),
                        hipFuncAttributeMaxDynamicSharedMemorySize, 73728);
    hipFuncSetAttribute(reinterpret_cast<const void*>(&gemm64<EPI_F32RES>),
                        hipFuncAttributeMaxDynamicSharedMemorySize, 73728);
  }

  const long MB = 1 << 20;
  char* ws = (char*)d_ws;
  char* ob = (char*)d_out;
  // ws (peak 56 MB): 0-6 WQKV [3072,1024] | 6-8 WO | 8-16 W1 | 16-24 W2 |
  //                  24-56 H (LN1 out, overwritten per-batch by A) ; FFN: 0-8 H2m, 24-56 Fm
  bf16* WQKV = (bf16*)(ws + 0 * MB);
  bf16* WO   = (bf16*)(ws + 6 * MB);
  bf16* W1   = (bf16*)(ws + 8 * MB);    // [4096,1024]
  bf16* W2   = (bf16*)(ws + 16 * MB);   // [1024,4096]
  bf16* H    = (bf16*)(ws + 24 * MB);   // [16384,1024]; batch z slice becomes A_z
  // d_out (64 MB, dead before X1): 0-32 P | 32-56 QKVb [4096,3072] | 56-64 Vt [1024,4096]
  bf16* P    = (bf16*)(ob + 0 * MB);
  bf16* QKVb = (bf16*)(ob + 32 * MB);
  bf16* Vt   = (bf16*)(ob + 56 * MB);
  float* OUT = (float*)d_out;
  const dim3 blk(256);
  const size_t SMEM64 = 73728;

  // 1. weight convert+transpose to [N,K] bf16 (QKV concatenated)
  convT_kernel<<<dim3(32, 32), blk, 0, stream>>>(wq, WQKV, 1024, 1024);
  convT_kernel<<<dim3(32, 32), blk, 0, stream>>>(wk, WQKV + 1024 * 1024, 1024, 1024);
  convT_kernel<<<dim3(32, 32), blk, 0, stream>>>(wv, WQKV + 2048 * 1024, 1024, 1024);
  convT_kernel<<<dim3(32, 32), blk, 0, stream>>>(wo, WO, 1024, 1024);
  convT_kernel<<<dim3(128, 32), blk, 0, stream>>>(w1, W1, 1024, 4096);
  convT_kernel<<<dim3(32, 128), blk, 0, stream>>>(w2, W2, 4096, 1024);
  // 2. LN1 -> H (bf16), all rows
  ln_bf16_kernel<<<16384, blk, 0, stream>>>(x, g1, be1, H);
  // 3. attention per batch
  for (int z = 0; z < 4; z++) {
    const long zo = (long)z * 4096 * 1024;
    // fused QKV: [4096,3072] = H_z @ WQKV^T + (bq|bk|bv)  (768 blocks, 2-resident)
    gemm128<EPI_QKV><<<dim3(24, 32), blk, 0, stream>>>(
        H + zo, WQKV, bq, bk, bv, nullptr, QKVb,
        4096, 3072, 1024, 1024, 1024, 3072, 1.0f);
    // V part -> Vt [1024,4096]
    transpose_bf16<<<dim3(32, 128), blk, 0, stream>>>(QKVb + 2048, Vt, 3072, 4096);
    // scores = Q K^T / 32  (1024 blocks, 2-resident)
    gemm128<EPI_BF16><<<dim3(32, 32), blk, 0, stream>>>(
        QKVb, QKVb + 1024, nullptr, nullptr, nullptr, nullptr, P,
        4096, 4096, 1024, 3072, 3072, 4096, 1.0f / 32.0f);
    softmax_kernel<<<4096, blk, 0, stream>>>(P);
    // A_z = P @ V -> overwrite H_z  (512 blocks, 2-resident + deep prefetch)
    gemm64<EPI_BF16><<<dim3(8, 64), blk, SMEM64, stream>>>(
        P, Vt, nullptr, nullptr, H + zo,
        4096, 1024, 4096, 4096, 4096, 1024, 1.0f);
  }
  // 4. X1 = x + A @ WO^T + bo -> d_out  (1024 blocks, 2-resident)
  gemm128<EPI_F32RES><<<dim3(8, 128), blk, 0, stream>>>(
      H, WO, bo, nullptr, nullptr, x, OUT,
      16384, 1024, 1024, 1024, 1024, 1024, 1.0f);
  // 5. FFN in M-chunks of 4096 rows
  bf16* H2m = (bf16*)(ws + 0 * MB);   // over dead WQKV+WO (8 MB)
  bf16* Fm  = (bf16*)(ws + 24 * MB);  // over dead A (32 MB)
  for (int mc = 0; mc < 4; mc++) {
    const long ro = (long)mc * 4096 * 1024;
    ln_bf16_kernel<<<4096, blk, 0, stream>>>(OUT + ro, g2, be2, H2m);
    gemm128<EPI_GELU><<<dim3(32, 32), blk, 0, stream>>>(
        H2m, W1, b1, nullptr, nullptr, nullptr, Fm,
        4096, 4096, 1024, 1024, 1024, 4096, 1.0f);
    gemm64<EPI_F32RES><<<dim3(8, 64), blk, SMEM64, stream>>>(
        Fm, W2, b2, OUT + ro, OUT + ro,
        4096, 1024, 4096, 4096, 4096, 1024, 1.0f);
  }
  (void)in_sizes; (void)n_in; (void)out_size; (void)ws_size;
}

// Round 7
// 1199.416 us; speedup vs baseline: 1.1095x; 1.1095x over previous
//
#include <hip/hip_runtime.h>
#include <hip/hip_bf16.h>
#include <cstdint>

typedef __bf16 bf16;
typedef __bf16 bf16x8 __attribute__((ext_vector_type(8)));
typedef __bf16 bf16x4 __attribute__((ext_vector_type(4)));
typedef float f32x4 __attribute__((ext_vector_type(4)));

#define DEV __device__ __forceinline__

DEV float wred_sum(float v) {
#pragma unroll
  for (int off = 32; off > 0; off >>= 1) v += __shfl_xor(v, off, 64);
  return v;
}
DEV float wred_max(float v) {
#pragma unroll
  for (int off = 32; off > 0; off >>= 1) v = fmaxf(v, __shfl_xor(v, off, 64));
  return v;
}

// ---------------- weight convert + transpose: in [K,N] f32 -> out [N,K] bf16
__global__ void convT_kernel(const float* __restrict__ in, bf16* __restrict__ out,
                             int K, int N) {
  __shared__ float t[32][33];
  const int n0 = blockIdx.x * 32, k0 = blockIdx.y * 32;
  const int tx = threadIdx.x & 31, ty = threadIdx.x >> 5;  // 32x8
#pragma unroll
  for (int i = 0; i < 4; i++)
    t[ty + 8 * i][tx] = in[(long)(k0 + ty + 8 * i) * N + n0 + tx];
  __syncthreads();
#pragma unroll
  for (int i = 0; i < 4; i++)
    out[(long)(n0 + ty + 8 * i) * K + k0 + tx] = (bf16)t[tx][ty + 8 * i];
}

// ---------------- bf16 transpose: in [R,C] (ldin) -> out [C,R] (ldout)
__global__ void transpose_bf16(const bf16* __restrict__ in, bf16* __restrict__ out,
                               int ldin, int ldout) {
  __shared__ bf16 t[32][33];
  const int c0 = blockIdx.x * 32, r0 = blockIdx.y * 32;
  const int tx = threadIdx.x & 31, ty = threadIdx.x >> 5;  // 32x8
#pragma unroll
  for (int i = 0; i < 4; i++)
    t[ty + 8 * i][tx] = in[(long)(r0 + ty + 8 * i) * ldin + c0 + tx];
  __syncthreads();
#pragma unroll
  for (int i = 0; i < 4; i++)
    out[(long)(c0 + ty + 8 * i) * ldout + r0 + tx] = t[tx][ty + 8 * i];
}

// ---------------- layernorm (row=1024) f32 -> bf16
__global__ void ln_bf16_kernel(const float* __restrict__ x, const float* __restrict__ g,
                               const float* __restrict__ be, bf16* __restrict__ out) {
  const long row = blockIdx.x;
  const int tid = threadIdx.x;  // 256
  const float4 v = ((const float4*)(x + row * 1024))[tid];
  float s = v.x + v.y + v.z + v.w;
  float s2 = v.x * v.x + v.y * v.y + v.z * v.z + v.w * v.w;
  __shared__ float rs_[4], rs2_[4];
  s = wred_sum(s);
  s2 = wred_sum(s2);
  const int wave = tid >> 6, lane = tid & 63;
  if (lane == 0) { rs_[wave] = s; rs2_[wave] = s2; }
  __syncthreads();
  s = rs_[0] + rs_[1] + rs_[2] + rs_[3];
  s2 = rs2_[0] + rs2_[1] + rs2_[2] + rs2_[3];
  const float mu = s * (1.0f / 1024.0f);
  const float var = s2 * (1.0f / 1024.0f) - mu * mu;
  const float rstd = rsqrtf(var + 1e-5f);
  const float4 gg = ((const float4*)g)[tid];
  const float4 bb = ((const float4*)be)[tid];
  bf16x4 o;
  o[0] = (bf16)((v.x - mu) * rstd * gg.x + bb.x);
  o[1] = (bf16)((v.y - mu) * rstd * gg.y + bb.y);
  o[2] = (bf16)((v.z - mu) * rstd * gg.z + bb.z);
  o[3] = (bf16)((v.w - mu) * rstd * gg.w + bb.w);
  *(bf16x4*)(out + row * 1024 + tid * 4) = o;
}

// ---------------- softmax over rows of 4096, in-place bf16
__global__ void softmax_kernel(bf16* __restrict__ p) {
  const long row = blockIdx.x;
  bf16* pr = p + row * 4096;
  const int tid = threadIdx.x;  // 256, 16 elems each
  bf16x8 a = *(const bf16x8*)(pr + tid * 16);
  bf16x8 b = *(const bf16x8*)(pr + tid * 16 + 8);
  float v[16];
#pragma unroll
  for (int i = 0; i < 8; i++) { v[i] = (float)a[i]; v[8 + i] = (float)b[i]; }
  float mx = -1e30f;
#pragma unroll
  for (int i = 0; i < 16; i++) mx = fmaxf(mx, v[i]);
  __shared__ float red1[4], red2[4];
  mx = wred_max(mx);
  const int wave = tid >> 6, lane = tid & 63;
  if (lane == 0) red1[wave] = mx;
  __syncthreads();
  mx = fmaxf(fmaxf(red1[0], red1[1]), fmaxf(red1[2], red1[3]));
  float s = 0.0f;
#pragma unroll
  for (int i = 0; i < 16; i++) { v[i] = __expf(v[i] - mx); s += v[i]; }
  s = wred_sum(s);
  if (lane == 0) red2[wave] = s;
  __syncthreads();
  s = red2[0] + red2[1] + red2[2] + red2[3];
  const float inv = 1.0f / s;
#pragma unroll
  for (int i = 0; i < 8; i++) { a[i] = (bf16)(v[i] * inv); b[i] = (bf16)(v[8 + i] * inv); }
  *(bf16x8*)(pr + tid * 16) = a;
  *(bf16x8*)(pr + tid * 16 + 8) = b;
}

enum { EPI_BF16 = 0, EPI_QKV = 1, EPI_GELU = 2, EPI_F32RES = 3 };

DEV void stage16(const bf16* g, bf16* l) {
  __builtin_amdgcn_global_load_lds((const __attribute__((address_space(1))) void*)g,
                                   (__attribute__((address_space(3))) void*)l, 16, 0, 0);
}

DEV int xcd_swizzle(int flat, int nwg) {
  const int qq = nwg >> 3, rr = nwg & 7;
  const int xcd = flat & 7, idx = flat >> 3;
  return (xcd < rr ? xcd * (qq + 1) : rr * (qq + 1) + (xcd - rr) * qq) + idx;
}

// ---------------- 64x128 triple-buffered NT GEMM, 2-tiles-ahead (PV, W2)
// grid (8,64) = 512 blocks = 2 resident/CU (LDS 72 KiB) + counted vmcnt(6).
// NO sched_barrier(0) pinning (m141: order-pinning costs ~40%); ordering by
// s_barrier side-effects + asm vmcnt "memory" clobber + compiler waitcnts.
template <int EPI>
__global__ __launch_bounds__(256, 2)
void gemm64(const bf16* __restrict__ A, const bf16* __restrict__ B,
            const float* __restrict__ bias, const float* __restrict__ resid,
            void* Cout, int M, int N, int K,
            int lda, int ldb, int ldc, float alpha) {
  extern __shared__ __align__(16) char smem[];
  bf16* sA = (bf16*)smem;        // 3 bufs x 4096 bf16 (64 rows x 64)
  bf16* sB = sA + 3 * 4096;      // 3 bufs x 8192 bf16 (128 rows x 64)
  int flat = (int)(blockIdx.y * gridDim.x + blockIdx.x);
  flat = xcd_swizzle(flat, (int)(gridDim.x * gridDim.y));
  const int bix = flat % (int)gridDim.x, biy = flat / (int)gridDim.x;
  const int tid = threadIdx.x;
  const int lane = tid & 63;
  const int wid = tid >> 6;          // 0..3
  const int q = lane >> 4, r16 = lane & 15;
  const int wr = wid >> 1, wc = wid & 1;   // wr: 32-row band, wc: 64-col band
  const long m0 = (long)biy * 64;
  const long n0 = (long)bix * 128;
  const int srow = tid >> 3;         // 0..31
  const int gcol = ((tid & 7) ^ (srow & 7)) * 8;
  const long lda32 = (long)lda * 32, ldb32 = (long)ldb * 32;
  const bf16* Ag = A + (m0 + srow) * (long)lda + gcol;
  const bf16* Bg = B + (n0 + srow) * (long)ldb + gcol;
  const int NT = K >> 6;
  const int swz = r16 * 64 + ((q ^ (r16 & 7)) * 8);
  const int abase = wr * 2048 + swz;   // 32-row band
  const int bbase = wc * 4096 + swz;   // 64-row band
  f32x4 acc[2][4] = {};

  // prologue: tiles 0,1 -> bufs 0,1 (6 loads each: 2 A-blocks + 4 B-blocks)
  const int PRE = NT < 2 ? NT : 2;
  for (int tt = 0; tt < PRE; ++tt) {
#pragma unroll
    for (int blk = 0; blk < 2; ++blk)
      stage16(Ag + tt * 64 + blk * lda32, sA + tt * 4096 + tid * 8 + blk * 2048);
#pragma unroll
    for (int blk = 0; blk < 4; ++blk)
      stage16(Bg + tt * 64 + blk * ldb32, sB + tt * 8192 + tid * 8 + blk * 2048);
  }
  if (NT >= 2) asm volatile("s_waitcnt vmcnt(6)" ::: "memory");
  else         asm volatile("s_waitcnt vmcnt(0)" ::: "memory");
  __builtin_amdgcn_s_barrier();

  int bxA = 0, bxB = 0;          // compute-buf offsets (t%3)
  int bsA = 8192, bsB = 16384;   // stage-buf offsets ((t+2)%3)
  for (int t = 0; t < NT; ++t) {
    if (t + 2 < NT) {   // stage tile t+2 (its buf's last read was tile t-1)
      const bf16* Agn = Ag + (t + 2) * 64;
      const bf16* Bgn = Bg + (t + 2) * 64;
#pragma unroll
      for (int blk = 0; blk < 2; ++blk)
        stage16(Agn + blk * lda32, sA + bsA + tid * 8 + blk * 2048);
#pragma unroll
      for (int blk = 0; blk < 4; ++blk)
        stage16(Bgn + blk * ldb32, sB + bsB + tid * 8 + blk * 2048);
    }
    const bf16* sAb = sA + bxA;
    const bf16* sBb = sB + bxB;
    bf16x8 a0[2], a1[2], b0[4], b1[4];
#pragma unroll
    for (int i = 0; i < 2; ++i) {
      a0[i] = *(const bf16x8*)(sAb + (abase + i * 1024));
      a1[i] = *(const bf16x8*)(sAb + ((abase + i * 1024) ^ 32));
    }
#pragma unroll
    for (int j = 0; j < 4; ++j) {
      b0[j] = *(const bf16x8*)(sBb + (bbase + j * 1024));
      b1[j] = *(const bf16x8*)(sBb + ((bbase + j * 1024) ^ 32));
    }
    __builtin_amdgcn_s_setprio(1);
#pragma unroll
    for (int i = 0; i < 2; ++i)
#pragma unroll
      for (int j = 0; j < 4; ++j) {
        acc[i][j] = __builtin_amdgcn_mfma_f32_16x16x32_bf16(b0[j], a0[i], acc[i][j], 0, 0, 0);
        acc[i][j] = __builtin_amdgcn_mfma_f32_16x16x32_bf16(b1[j], a1[i], acc[i][j], 0, 0, 0);
      }
    __builtin_amdgcn_s_setprio(0);
    if (t + 2 < NT)      asm volatile("s_waitcnt vmcnt(6)" ::: "memory");
    else if (t + 1 < NT) asm volatile("s_waitcnt vmcnt(0)" ::: "memory");
    if (t + 1 < NT) __builtin_amdgcn_s_barrier();
    bxA += 4096; if (bxA == 12288) bxA = 0;
    bxB += 8192; if (bxB == 24576) bxB = 0;
    bsA += 4096; if (bsA == 12288) bsA = 0;
    bsB += 8192; if (bsB == 24576) bsB = 0;
  }

  // epilogue
#pragma unroll
  for (int i = 0; i < 2; ++i) {
    const long row = m0 + wr * 32 + i * 16 + r16;
#pragma unroll
    for (int j = 0; j < 4; ++j) {
      const int ncol = (int)n0 + wc * 64 + j * 16 + q * 4;
      float4 b4 = make_float4(0.f, 0.f, 0.f, 0.f);
      if (bias != nullptr) b4 = *(const float4*)(bias + ncol);
      float v0 = acc[i][j][0] * alpha + b4.x;
      float v1 = acc[i][j][1] * alpha + b4.y;
      float v2 = acc[i][j][2] * alpha + b4.z;
      float v3 = acc[i][j][3] * alpha + b4.w;
      if (EPI == EPI_F32RES) {
        const long idx = row * (long)ldc + ncol;
        const float4 rr = *(const float4*)(resid + idx);
        const float4 o = make_float4(v0 + rr.x, v1 + rr.y, v2 + rr.z, v3 + rr.w);
        *(float4*)((float*)Cout + idx) = o;
      } else {
        bf16x4 o;
        o[0] = (bf16)v0; o[1] = (bf16)v1; o[2] = (bf16)v2; o[3] = (bf16)v3;
        *(bf16x4*)((bf16*)Cout + row * (long)ldc + ncol) = o;
      }
    }
  }
}

// ---------------- 256x256 8-phase NT GEMM (deep-slack, counted vmcnt, setprio)
// NO sched_barrier(0) pinning (the single change vs R5 — m141 mechanism).
// Stage slots (tile t): p0 A#2(t+1)->other buf | p1 B-lo(t+2)->this buf |
// p2 A#1(t+2)->this buf | p3 B-hi(t+2)->this buf. Waits: vmcnt(10)@p1,
// vmcnt(8)@p3 (tails: p1 {NT-2:8, NT-1:0}, p3 {NT-2:2}).
template <int EPI>
__global__ __launch_bounds__(512, 2)
void gemm256(const bf16* __restrict__ A, const bf16* __restrict__ B,
             const float* __restrict__ bias, const float* bias2, const float* bias3,
             const float* resid, void* Cout, int M, int N, int K,
             int lda, int ldb, int ldc, float alpha) {
  extern __shared__ __align__(16) char smem[];
  bf16* sA = (bf16*)smem;   // [2 buf][256 rows][64] bf16 = 64 KiB
  bf16* sB = sA + 32768;    // 64 KiB
  const int tid = threadIdx.x;
  const int lane = tid & 63;
  const int wid = tid >> 6;
  const int q = lane >> 4, r16 = lane & 15;
  const int wr = wid >> 2, wc = wid & 3;
  const long m0 = (long)blockIdx.y * 256;
  const long n0 = (long)blockIdx.x * 256;
  const int srow = tid >> 3;                      // 0..63 per 64-row block
  const int gcol = ((tid & 7) ^ (srow & 7)) * 8;  // pre-swizzled source chunk
  const long lda64 = (long)lda * 64, ldb64 = (long)ldb * 64;
  const bf16* AgT = A + (m0 + srow) * (long)lda + gcol;
  const bf16* BgT = B + (n0 + srow) * (long)ldb + gcol;
  bf16* lA = sA + tid * 8;  // linear LDS dest (buf0, block0)
  bf16* lB = sB + tid * 8;
  const int NT = K >> 6;
  const int swz = r16 * 64 + ((q ^ (r16 & 7)) * 8);
  const int abase = wr * 8192 + swz;
  const int bbase = (wc >> 1) * 8192 + (wc & 1) * 4096 + swz;

  f32x4 acc[8][4] = {};

  // ---- prologue (order defines the vmcnt queue):
  //  A0#1(2), A0#2(2), B0(4), A1#1(2), B1(4), A1#2(2); vmcnt(8) -> A0+B0 landed
  stage16(AgT,              lA);
  stage16(AgT + 2 * lda64,  lA + 8192);
  stage16(AgT + lda64,      lA + 4096);
  stage16(AgT + 3 * lda64,  lA + 12288);
  stage16(BgT,              lB);
  stage16(BgT + ldb64,      lB + 4096);
  stage16(BgT + 2 * ldb64,  lB + 8192);
  stage16(BgT + 3 * ldb64,  lB + 12288);
  if (NT > 1) {
    stage16(AgT + 64,             lA + 16384);
    stage16(AgT + 64 + 2 * lda64, lA + 16384 + 8192);
    stage16(BgT + 64,             lB + 16384);
    stage16(BgT + 64 + ldb64,     lB + 16384 + 4096);
    stage16(BgT + 64 + 2 * ldb64, lB + 16384 + 8192);
    stage16(BgT + 64 + 3 * ldb64, lB + 16384 + 12288);
    stage16(AgT + 64 + lda64,     lA + 16384 + 4096);
    stage16(AgT + 64 + 3 * lda64, lA + 16384 + 12288);
    asm volatile("s_waitcnt vmcnt(8)" ::: "memory");
  } else {
    asm volatile("s_waitcnt vmcnt(0)" ::: "memory");
  }
  __builtin_amdgcn_s_barrier();

  for (int t = 0; t < NT; ++t) {
    const int bx = (t & 1) * 16384;   // A(t),B(t) live here
    const int nbx = 16384 - bx;
    const bf16* sAb = sA + bx;
    const bf16* sBb = sB + bx;
    const long k1 = (long)(t + 1) * 64;
    const long k2 = (long)(t + 2) * 64;
    bf16x8 b0[4], b1[4];              // B-frags, live for the whole tile
#pragma unroll
    for (int p = 0; p < 4; ++p) {
      if (p == 0) {
#pragma unroll
        for (int n = 0; n < 4; ++n) {
          b0[n] = *(const bf16x8*)(sBb + (bbase + n * 1024));
          b1[n] = *(const bf16x8*)(sBb + ((bbase + n * 1024) ^ 32));
        }
      }
      const int ab = abase + p * 2048;
      const bf16x8 a00 = *(const bf16x8*)(sAb + ab);
      const bf16x8 a10 = *(const bf16x8*)(sAb + (ab ^ 32));
      const bf16x8 a01 = *(const bf16x8*)(sAb + (ab + 1024));
      const bf16x8 a11 = *(const bf16x8*)(sAb + ((ab + 1024) ^ 32));
      if (p == 0 && t >= 1 && t + 1 < NT) {   // A#2(t+1) -> other buf (rows freed @ t-1,p3)
        stage16(AgT + k1 + lda64,     lA + nbx + 4096);
        stage16(AgT + k1 + 3 * lda64, lA + nbx + 12288);
      }
      if (p == 1 && t + 2 < NT) {             // B-lo(t+2) -> this buf (freed @ p0)
        stage16(BgT + k2,         lB + bx);
        stage16(BgT + k2 + ldb64, lB + bx + 4096);
      }
      if (p == 2 && t + 2 < NT) {             // A#1(t+2) -> this buf (freed @ p1)
        stage16(AgT + k2,             lA + bx);
        stage16(AgT + k2 + 2 * lda64, lA + bx + 8192);
      }
      if (p == 3 && t + 2 < NT) {             // B-hi(t+2) -> this buf
        stage16(BgT + k2 + 2 * ldb64, lB + bx + 8192);
        stage16(BgT + k2 + 3 * ldb64, lB + bx + 12288);
      }
      __builtin_amdgcn_s_barrier();
      __builtin_amdgcn_s_setprio(1);
#pragma unroll
      for (int n = 0; n < 4; ++n) {
        acc[2 * p][n]     = __builtin_amdgcn_mfma_f32_16x16x32_bf16(b0[n], a00, acc[2 * p][n], 0, 0, 0);
        acc[2 * p][n]     = __builtin_amdgcn_mfma_f32_16x16x32_bf16(b1[n], a10, acc[2 * p][n], 0, 0, 0);
        acc[2 * p + 1][n] = __builtin_amdgcn_mfma_f32_16x16x32_bf16(b0[n], a01, acc[2 * p + 1][n], 0, 0, 0);
        acc[2 * p + 1][n] = __builtin_amdgcn_mfma_f32_16x16x32_bf16(b1[n], a11, acc[2 * p + 1][n], 0, 0, 0);
      }
      __builtin_amdgcn_s_setprio(0);
      if (p == 1) {  // need A#2(t) drained before p2 reads
        if (t + 2 < NT)      asm volatile("s_waitcnt vmcnt(10)" ::: "memory");
        else if (t + 1 < NT) asm volatile("s_waitcnt vmcnt(8)" ::: "memory");
        else                 asm volatile("s_waitcnt vmcnt(0)" ::: "memory");
      }
      if (p == 3) {  // need A#1(t+1)+B(t+1) drained before next tile
        if (t + 2 < NT)      asm volatile("s_waitcnt vmcnt(8)" ::: "memory");
        else if (t + 1 < NT) asm volatile("s_waitcnt vmcnt(2)" ::: "memory");
      }
      __builtin_amdgcn_s_barrier();
    }
  }

  // epilogue (C/D mapping: row = m-frag r16, 4 consecutive cols per lane)
#pragma unroll
  for (int m = 0; m < 8; ++m) {
    const long row = m0 + wr * 128 + m * 16 + r16;
#pragma unroll
    for (int n = 0; n < 4; ++n) {
      const int ncol = (int)n0 + wc * 64 + n * 16 + q * 4;
      float4 b4 = make_float4(0.f, 0.f, 0.f, 0.f);
      if (EPI == EPI_QKV) {
        const int band = ncol >> 10;
        const float* bsel = band == 0 ? bias : (band == 1 ? bias2 : bias3);
        b4 = *(const float4*)(bsel + (ncol & 1023));
      } else if (bias != nullptr) {
        b4 = *(const float4*)(bias + ncol);
      }
      float v0 = acc[m][n][0] * alpha + b4.x;
      float v1 = acc[m][n][1] * alpha + b4.y;
      float v2 = acc[m][n][2] * alpha + b4.z;
      float v3 = acc[m][n][3] * alpha + b4.w;
      if (EPI == EPI_GELU) {
        v0 = 0.5f * v0 * (1.0f + erff(v0 * 0.70710678118654752f));
        v1 = 0.5f * v1 * (1.0f + erff(v1 * 0.70710678118654752f));
        v2 = 0.5f * v2 * (1.0f + erff(v2 * 0.70710678118654752f));
        v3 = 0.5f * v3 * (1.0f + erff(v3 * 0.70710678118654752f));
      }
      if (EPI == EPI_F32RES) {
        const long idx = row * (long)ldc + ncol;
        const float4 rr = *(const float4*)(resid + idx);
        const float4 o = make_float4(v0 + rr.x, v1 + rr.y, v2 + rr.z, v3 + rr.w);
        *(float4*)((float*)Cout + idx) = o;
      } else {
        bf16x4 o;
        o[0] = (bf16)v0; o[1] = (bf16)v1; o[2] = (bf16)v2; o[3] = (bf16)v3;
        *(bf16x4*)((bf16*)Cout + row * (long)ldc + ncol) = o;
      }
    }
  }
}

extern "C" void kernel_launch(void* const* d_in, const int* in_sizes, int n_in,
                              void* d_out, int out_size, void* d_ws, size_t ws_size,
                              hipStream_t stream) {
  const float* x  = (const float*)d_in[0];
  const float* wq = (const float*)d_in[1];
  const float* bq = (const float*)d_in[2];
  const float* wk = (const float*)d_in[3];
  const float* bk = (const float*)d_in[4];
  const float* wv = (const float*)d_in[5];
  const float* bv = (const float*)d_in[6];
  const float* wo = (const float*)d_in[7];
  const float* bo = (const float*)d_in[8];
  const float* w1 = (const float*)d_in[9];
  const float* b1 = (const float*)d_in[10];
  const float* w2 = (const float*)d_in[11];
  const float* b2 = (const float*)d_in[12];
  const float* g1 = (const float*)d_in[13];
  const float* be1 = (const float*)d_in[14];
  const float* g2 = (const float*)d_in[15];
  const float* be2 = (const float*)d_in[16];

  // allow >64 KiB dynamic LDS (once per process)
  static int attr_done = 0;
  if (!attr_done) {
    attr_done = 1;
    hipFuncSetAttribute(reinterpret_cast<const void*>(&gemm256<EPI_QKV>),
                        hipFuncAttributeMaxDynamicSharedMemorySize, 131072);
    hipFuncSetAttribute(reinterpret_cast<const void*>(&gemm256<EPI_BF16>),
                        hipFuncAttributeMaxDynamicSharedMemorySize, 131072);
    hipFuncSetAttribute(reinterpret_cast<const void*>(&gemm256<EPI_GELU>),
                        hipFuncAttributeMaxDynamicSharedMemorySize, 131072);
    hipFuncSetAttribute(reinterpret_cast<const void*>(&gemm256<EPI_F32RES>),
                        hipFuncAttributeMaxDynamicSharedMemorySize, 131072);
    hipFuncSetAttribute(reinterpret_cast<const void*>(&gemm64<EPI_BF16>),
                        hipFuncAttributeMaxDynamicSharedMemorySize, 73728);
    hipFuncSetAttribute(reinterpret_cast<const void*>(&gemm64<EPI_F32RES>),
                        hipFuncAttributeMaxDynamicSharedMemorySize, 73728);
  }

  const long MB = 1 << 20;
  char* ws = (char*)d_ws;
  char* ob = (char*)d_out;
  // ws (peak 56 MB): 0-6 WQKV [3072,1024] | 6-8 WO | 8-16 W1 | 16-24 W2 |
  //                  24-56 H (LN1 out, overwritten per-batch by A) ; FFN: 0-8 H2m, 24-56 Fm
  bf16* WQKV = (bf16*)(ws + 0 * MB);
  bf16* WO   = (bf16*)(ws + 6 * MB);
  bf16* W1   = (bf16*)(ws + 8 * MB);    // [4096,1024]
  bf16* W2   = (bf16*)(ws + 16 * MB);   // [1024,4096]
  bf16* H    = (bf16*)(ws + 24 * MB);   // [16384,1024]; batch z slice becomes A_z
  // d_out (64 MB, dead before X1): 0-32 P | 32-56 QKVb [4096,3072] | 56-64 Vt [1024,4096]
  bf16* P    = (bf16*)(ob + 0 * MB);
  bf16* QKVb = (bf16*)(ob + 32 * MB);
  bf16* Vt   = (bf16*)(ob + 56 * MB);
  float* OUT = (float*)d_out;
  const dim3 blk(256);
  const dim3 blk512(512);
  const size_t SMEM = 131072;
  const size_t SMEM64 = 73728;

  // 1. weight convert+transpose to [N,K] bf16 (QKV concatenated)
  convT_kernel<<<dim3(32, 32), blk, 0, stream>>>(wq, WQKV, 1024, 1024);
  convT_kernel<<<dim3(32, 32), blk, 0, stream>>>(wk, WQKV + 1024 * 1024, 1024, 1024);
  convT_kernel<<<dim3(32, 32), blk, 0, stream>>>(wv, WQKV + 2048 * 1024, 1024, 1024);
  convT_kernel<<<dim3(32, 32), blk, 0, stream>>>(wo, WO, 1024, 1024);
  convT_kernel<<<dim3(128, 32), blk, 0, stream>>>(w1, W1, 1024, 4096);
  convT_kernel<<<dim3(32, 128), blk, 0, stream>>>(w2, W2, 4096, 1024);
  // 2. LN1 -> H (bf16), all rows
  ln_bf16_kernel<<<16384, blk, 0, stream>>>(x, g1, be1, H);
  // 3. attention per batch
  for (int z = 0; z < 4; z++) {
    const long zo = (long)z * 4096 * 1024;
    // fused QKV: [4096,3072] = H_z @ WQKV^T + (bq|bk|bv)
    gemm256<EPI_QKV><<<dim3(12, 16), blk512, SMEM, stream>>>(
        H + zo, WQKV, bq, bk, bv, nullptr, QKVb,
        4096, 3072, 1024, 1024, 1024, 3072, 1.0f);
    // V part -> Vt [1024,4096]
    transpose_bf16<<<dim3(32, 128), blk, 0, stream>>>(QKVb + 2048, Vt, 3072, 4096);
    // scores = Q K^T / 32
    gemm256<EPI_BF16><<<dim3(16, 16), blk512, SMEM, stream>>>(
        QKVb, QKVb + 1024, nullptr, nullptr, nullptr, nullptr, P,
        4096, 4096, 1024, 3072, 3072, 4096, 1.0f / 32.0f);
    softmax_kernel<<<4096, blk, 0, stream>>>(P);
    // A_z = P @ V -> overwrite H_z  (512 blocks, 2-resident + deep prefetch)
    gemm64<EPI_BF16><<<dim3(8, 64), blk, SMEM64, stream>>>(
        P, Vt, nullptr, nullptr, H + zo,
        4096, 1024, 4096, 4096, 4096, 1024, 1.0f);
  }
  // 4. X1 = x + A @ WO^T + bo -> d_out (attention scratch dead)
  gemm256<EPI_F32RES><<<dim3(4, 64), blk512, SMEM, stream>>>(
      H, WO, bo, nullptr, nullptr, x, OUT,
      16384, 1024, 1024, 1024, 1024, 1024, 1.0f);
  // 5. FFN in M-chunks of 4096 rows
  bf16* H2m = (bf16*)(ws + 0 * MB);   // over dead WQKV+WO (8 MB)
  bf16* Fm  = (bf16*)(ws + 24 * MB);  // over dead A (32 MB)
  for (int mc = 0; mc < 4; mc++) {
    const long ro = (long)mc * 4096 * 1024;
    ln_bf16_kernel<<<4096, blk, 0, stream>>>(OUT + ro, g2, be2, H2m);
    gemm256<EPI_GELU><<<dim3(16, 16), blk512, SMEM, stream>>>(
        H2m, W1, b1, nullptr, nullptr, nullptr, Fm,
        4096, 4096, 1024, 1024, 1024, 4096, 1.0f);
    gemm64<EPI_F32RES><<<dim3(8, 64), blk, SMEM64, stream>>>(
        Fm, W2, b2, OUT + ro, OUT + ro,
        4096, 1024, 4096, 4096, 4096, 1024, 1.0f);
  }
  (void)in_sizes; (void)n_in; (void)out_size; (void)ws_size;
}